// Round 1
// baseline (83.351 us; speedup 1.0000x reference)
//
#include <hip/hip_runtime.h>
#include <hip/hip_bf16.h>

// Problem constants
#define BDIM 8
#define CIN 32
#define COUT 32
#define HDIM 128
#define WDIM 128
#define JDIM (HDIM * WDIM)   // 16384
#define SDIM 1024
#define PARTS 16             // S split across blocks for gather parallelism
#define SPP (SDIM / PARTS)   // 64 samples per part

// ws layout (floats):
//   [0 .. PARTS*BDIM*96)          partials[part][b][i*3 + {P,Q0,Q1}]
//   [PARTS*BDIM*96 .. +768)       tk: T0[256] | T1[256] | C0[256]  (C0 = -(T0+T1+K))
#define PARTIALS_FLOATS (PARTS * BDIM * 96)

// ---------------------------------------------------------------------------
// Kernel 1: gather-reduce over sampled pixels.
// grid = BDIM*PARTS blocks, 256 threads.
// thread t: i = t&31 (input channel), sg = t>>5 (one of 8 s-subgroups).
// ---------------------------------------------------------------------------
__global__ __launch_bounds__(256) void k_gather(const float* __restrict__ v,
                                                const int* __restrict__ idx,
                                                float* __restrict__ partials) {
    const int b    = blockIdx.x / PARTS;
    const int part = blockIdx.x % PARTS;
    const int i    = threadIdx.x & 31;
    const int sg   = threadIdx.x >> 5;   // 0..7

    const float* vb = v + ((size_t)(b * CIN + i)) * JDIM;

    float p = 0.f, q0 = 0.f, q1 = 0.f;
    const float step = 2.0f / 127.0f;

    const int s0 = part * SPP;
#pragma unroll 4
    for (int s = s0 + sg; s < s0 + SPP; s += 8) {
        const int j = idx[s];            // 0..16383
        const int x = j & (WDIM - 1);
        const int y = j >> 7;
        const float scx = -1.0f + (float)x * step;
        const float scy = -1.0f + (float)y * step;
        const float val = vb[j];
        p  += val;
        q0 += val * scx;
        q1 += val * scy;
    }

    __shared__ float red[8][96];
    red[sg][i * 3 + 0] = p;
    red[sg][i * 3 + 1] = q0;
    red[sg][i * 3 + 2] = q1;
    __syncthreads();

    if (threadIdx.x < 96) {
        float sum = 0.f;
#pragma unroll
        for (int g = 0; g < 8; ++g) sum += red[g][threadIdx.x];
        partials[((size_t)part * BDIM + b) * 96 + threadIdx.x] = sum;
    }
}

// ---------------------------------------------------------------------------
// Kernel 2: reduce partials across parts, contract with weight.
// 1 block, 256 threads: t = b*32 + o.
// Outputs tk: T0 | T1 | C0 where C0 = -(T0 + T1 + K).
// ---------------------------------------------------------------------------
__global__ __launch_bounds__(256) void k_tk(const float* __restrict__ partials,
                                            const float* __restrict__ w,
                                            float* __restrict__ tk) {
    __shared__ float pq[BDIM][96];   // [b][i*3 + {P,Q0,Q1}]

    for (int slot = threadIdx.x; slot < BDIM * 96; slot += 256) {
        float s = 0.f;
#pragma unroll
        for (int part = 0; part < PARTS; ++part)
            s += partials[(size_t)part * BDIM * 96 + slot];
        pq[slot / 96][slot % 96] = s;
    }
    __syncthreads();

    const int b = threadIdx.x >> 5;
    const int o = threadIdx.x & 31;

    float t0 = 0.f, t1 = 0.f, k = 0.f;
#pragma unroll
    for (int i = 0; i < CIN; ++i) {
        const float P  = pq[b][i * 3 + 0];
        const float Q0 = pq[b][i * 3 + 1];
        const float Q1 = pq[b][i * 3 + 2];
        const float w0 = w[(o * CIN + i) * 2 + 0];
        const float w1 = w[(o * CIN + i) * 2 + 1];
        t0 += P * w0;
        t1 += P * w1;
        k  += Q0 * w0 + Q1 * w1;
    }
    tk[threadIdx.x]       = t0;
    tk[256 + threadIdx.x] = t1;
    tk[512 + threadIdx.x] = -(t0 + t1 + k);
}

// ---------------------------------------------------------------------------
// Kernel 3: streaming output fill.
// grid = 1024 blocks (256 (b,o) planes x 4 quarters), 256 threads.
// out[bo][r] = x * (2/127) * T0 + y * (2/127) * T1 + C0
// 4 x float4 stores per thread, fully coalesced.
// ---------------------------------------------------------------------------
__global__ __launch_bounds__(256) void k_out(const float* __restrict__ tk,
                                             float* __restrict__ out) {
    const int bo      = blockIdx.x >> 2;   // 0..255 = b*32+o
    const int quarter = blockIdx.x & 3;

    const float T0 = tk[bo];
    const float T1 = tk[256 + bo];
    const float C0 = tk[512 + bo];
    const float a  = T0 * (2.0f / 127.0f);
    const float c  = T1 * (2.0f / 127.0f);

    float* outp = out + (size_t)bo * JDIM;
    const int r0 = quarter * (JDIM / 4);   // 4096-aligned

#pragma unroll
    for (int seg = 0; seg < 4; ++seg) {
        const int r = r0 + (seg * 256 + threadIdx.x) * 4;
        const int x = r & (WDIM - 1);      // r%4==0 so row never splits a float4
        const int y = r >> 7;
        const float base = (float)y * c + C0;
        float4 val;
        val.x = base + (float)(x + 0) * a;
        val.y = base + (float)(x + 1) * a;
        val.z = base + (float)(x + 2) * a;
        val.w = base + (float)(x + 3) * a;
        *reinterpret_cast<float4*>(outp + r) = val;
    }
}

// ---------------------------------------------------------------------------
extern "C" void kernel_launch(void* const* d_in, const int* in_sizes, int n_in,
                              void* d_out, int out_size, void* d_ws, size_t ws_size,
                              hipStream_t stream) {
    const float* v   = (const float*)d_in[0];
    const float* w   = (const float*)d_in[1];
    const int*   idx = (const int*)d_in[2];
    float* out = (float*)d_out;

    float* partials = (float*)d_ws;
    float* tk       = partials + PARTIALS_FLOATS;

    k_gather<<<BDIM * PARTS, 256, 0, stream>>>(v, idx, partials);
    k_tk<<<1, 256, 0, stream>>>(partials, w, tk);
    k_out<<<1024, 256, 0, stream>>>(tk, out);
}

// Round 2
// 77.371 us; speedup vs baseline: 1.0773x; 1.0773x over previous
//
#include <hip/hip_runtime.h>
#include <hip/hip_bf16.h>

// Problem constants
#define BDIM 8
#define CIN 32
#define COUT 32
#define HDIM 128
#define WDIM 128
#define JDIM (HDIM * WDIM)   // 16384
#define SDIM 1024
#define PARTS 32             // S split across blocks for gather parallelism
#define SPP (SDIM / PARTS)   // 32 samples per part

// ws layout (floats): partials[part][b][i*3 + {P,Q0,Q1}]  (PARTS*BDIM*96 floats)

// ---------------------------------------------------------------------------
// Kernel 1: gather-reduce over sampled pixels.
// grid = BDIM*PARTS = 256 blocks (1 per CU), 256 threads.
// thread t: i = t&31 (input channel), sg = t>>5 (one of 8 s-subgroups).
// Each thread gathers SPP/8 = 4 independent samples (ILP for latency hiding).
// ---------------------------------------------------------------------------
__global__ __launch_bounds__(256) void k_gather(const float* __restrict__ v,
                                                const int* __restrict__ idx,
                                                float* __restrict__ partials) {
    const int b    = blockIdx.x >> 5;        // 0..7
    const int part = blockIdx.x & (PARTS - 1);
    const int i    = threadIdx.x & 31;
    const int sg   = threadIdx.x >> 5;       // 0..7

    const float* vb = v + ((size_t)(b * CIN + i)) * JDIM;
    const float step = 2.0f / 127.0f;

    // 4 fully independent gathers per thread
    const int s0 = part * SPP + sg;
    int j0 = idx[s0 + 0];
    int j1 = idx[s0 + 8];
    int j2 = idx[s0 + 16];
    int j3 = idx[s0 + 24];
    float v0 = vb[j0], v1 = vb[j1], v2 = vb[j2], v3 = vb[j3];

    float p = v0 + v1 + v2 + v3;
    float q0 = 0.f, q1 = 0.f;
    {
        const float x0 = -1.0f + (float)(j0 & (WDIM - 1)) * step;
        const float y0 = -1.0f + (float)(j0 >> 7) * step;
        const float x1 = -1.0f + (float)(j1 & (WDIM - 1)) * step;
        const float y1 = -1.0f + (float)(j1 >> 7) * step;
        const float x2 = -1.0f + (float)(j2 & (WDIM - 1)) * step;
        const float y2 = -1.0f + (float)(j2 >> 7) * step;
        const float x3 = -1.0f + (float)(j3 & (WDIM - 1)) * step;
        const float y3 = -1.0f + (float)(j3 >> 7) * step;
        q0 = v0 * x0 + v1 * x1 + v2 * x2 + v3 * x3;
        q1 = v0 * y0 + v1 * y1 + v2 * y2 + v3 * y3;
    }

    __shared__ float red[8][96];
    red[sg][i * 3 + 0] = p;
    red[sg][i * 3 + 1] = q0;
    red[sg][i * 3 + 2] = q1;
    __syncthreads();

    if (threadIdx.x < 96) {
        float sum = 0.f;
#pragma unroll
        for (int g = 0; g < 8; ++g) sum += red[g][threadIdx.x];
        partials[((size_t)part * BDIM + b) * 96 + threadIdx.x] = sum;
    }
}

// ---------------------------------------------------------------------------
// Kernel 2: per-(b,o) coefficient reduce + streaming output fill (fused).
// grid = 1024 blocks = 256 (b,o) planes x 4 quarters, 256 threads.
// Phase A: reduce partials over parts (96 floats, L2-hot), contract with w.
// Phase B: out[bo][r] = x*(2/127)*T0 + y*(2/127)*T1 + C0, 4x float4/thread.
// ---------------------------------------------------------------------------
__global__ __launch_bounds__(256) void k_out(const float* __restrict__ partials,
                                             const float* __restrict__ w,
                                             float* __restrict__ out) {
    const int bo      = blockIdx.x >> 2;   // 0..255 = b*32+o
    const int quarter = blockIdx.x & 3;
    const int b       = bo >> 5;
    const int o       = bo & 31;

    __shared__ float pq[96];
    __shared__ float coef[3];

    // Phase A1: sum partials over PARTS for this b
    if (threadIdx.x < 96) {
        float s = 0.f;
#pragma unroll
        for (int part = 0; part < PARTS; ++part)
            s += partials[((size_t)part * BDIM + b) * 96 + threadIdx.x];
        pq[threadIdx.x] = s;
    }
    __syncthreads();

    // Phase A2: 32-lane dot with weight row o, butterfly reduce
    if (threadIdx.x < 64) {
        const int i = threadIdx.x & 31;
        const float P  = pq[i * 3 + 0];
        const float Q0 = pq[i * 3 + 1];
        const float Q1 = pq[i * 3 + 2];
        const float w0 = w[(o * CIN + i) * 2 + 0];
        const float w1 = w[(o * CIN + i) * 2 + 1];
        float t0 = P * w0;
        float t1 = P * w1;
        float kk = Q0 * w0 + Q1 * w1;
#pragma unroll
        for (int off = 16; off >= 1; off >>= 1) {
            t0 += __shfl_xor(t0, off);
            t1 += __shfl_xor(t1, off);
            kk += __shfl_xor(kk, off);
        }
        if (threadIdx.x == 0) {
            const float step = 2.0f / 127.0f;
            coef[0] = t0 * step;          // x slope
            coef[1] = t1 * step;          // y slope
            coef[2] = -(t0 + t1 + kk);    // constant (coords offset -1 folded in)
        }
    }
    __syncthreads();

    const float a  = coef[0];
    const float c  = coef[1];
    const float C0 = coef[2];

    float* outp = out + (size_t)bo * JDIM;
    const int r0 = quarter * (JDIM / 4);   // 4096-aligned

#pragma unroll
    for (int seg = 0; seg < 4; ++seg) {
        const int r = r0 + (seg * 256 + threadIdx.x) * 4;
        const int x = r & (WDIM - 1);      // r%4==0 so a row never splits a float4
        const int y = r >> 7;
        const float base = (float)y * c + C0;
        float4 val;
        val.x = base + (float)(x + 0) * a;
        val.y = base + (float)(x + 1) * a;
        val.z = base + (float)(x + 2) * a;
        val.w = base + (float)(x + 3) * a;
        *reinterpret_cast<float4*>(outp + r) = val;
    }
}

// ---------------------------------------------------------------------------
extern "C" void kernel_launch(void* const* d_in, const int* in_sizes, int n_in,
                              void* d_out, int out_size, void* d_ws, size_t ws_size,
                              hipStream_t stream) {
    const float* v   = (const float*)d_in[0];
    const float* w   = (const float*)d_in[1];
    const int*   idx = (const int*)d_in[2];
    float* out = (float*)d_out;

    float* partials = (float*)d_ws;

    k_gather<<<BDIM * PARTS, 256, 0, stream>>>(v, idx, partials);
    k_out<<<1024, 256, 0, stream>>>(partials, w, out);
}